// Round 4
// baseline (428.279 us; speedup 1.0000x reference)
//
#include <hip/hip_runtime.h>

#define DIM   64
#define KCB   1024
#define NROWS 131072

// ws layout (floats): ws[0] = loss accumulator; ws[256 .. 256+1023] = csq[k]

// Precompute csq[k] = sum(cb[k]^2) mimicking numpy pairwise (8-acc) order,
// and zero the loss accumulator (ws is re-poisoned to 0xAA before every call).
__global__ void vq_prep(const float* __restrict__ cb, float* __restrict__ ws) {
    int k = blockIdx.x * blockDim.x + threadIdx.x;
    if (k < KCB) {
        const float* e = cb + (k << 6);
        {
            #pragma clang fp contract(off)
            float racc[8];
            #pragma unroll
            for (int j = 0; j < 8; ++j) racc[j] = e[j] * e[j];
            #pragma unroll
            for (int t = 1; t < 8; ++t) {
                #pragma unroll
                for (int j = 0; j < 8; ++j) racc[j] += e[8 * t + j] * e[8 * t + j];
            }
            ws[256 + k] = ((racc[0] + racc[1]) + (racc[2] + racc[3]))
                        + ((racc[4] + racc[5]) + (racc[6] + racc[7]));
        }
    }
    if (k == 0) ws[0] = 0.0f;
}

// Block = 256 threads: waves 0-1 scan k in [0,512) for rows r0..r0+127,
// waves 2-3 scan k in [512,1024) for the same rows.
//  - kbase via readfirstlane -> codebook loads scalarize (s_load broadcast).
//  - 4 codebook entries per iteration: each x[j] access (VGPR or AGPR-parked
//    accvgpr_read -- R3 showed the allocator parks x[64] in AGPRs at
//    VGPR_Count=40 and pays one read per fmac) now feeds 4 fmacs, cutting
//    the non-FMA VALU overhead from ~1x to ~0.25x per fmac.
//  - per-dot accumulation order unchanged (sequential j fma chain);
//    min-scan ascending k, strict < -> bit-identical to R1/R3 results.
__global__ __launch_bounds__(256, 4) void vq_argmin(
        const float* __restrict__ in,
        const float* __restrict__ cb,
        const float* __restrict__ csq,      // = ws + 256
        float* __restrict__ codes_f,
        float* __restrict__ loss_acc)       // = ws + 0
{
    const int tid  = threadIdx.x;
    const int half = tid >> 7;              // wave-uniform (waves 0,1 -> 0; 2,3 -> 1)
    const int lr   = tid & 127;
    const int row  = blockIdx.x * 128 + lr;

    const float4* x4p = (const float4*)(in + (size_t)row * DIM);
    float x[64];
    #pragma unroll
    for (int i = 0; i < 16; ++i) {
        float4 v = x4p[i];
        x[4 * i + 0] = v.x; x[4 * i + 1] = v.y;
        x[4 * i + 2] = v.z; x[4 * i + 3] = v.w;
    }

    // A = ||x||^2, numpy pairwise 8-accumulator order, squares rounded separately
    float A;
    {
        #pragma clang fp contract(off)
        float racc[8];
        #pragma unroll
        for (int j = 0; j < 8; ++j) racc[j] = x[j] * x[j];
        #pragma unroll
        for (int t = 1; t < 8; ++t) {
            #pragma unroll
            for (int j = 0; j < 8; ++j) racc[j] += x[8 * t + j] * x[8 * t + j];
        }
        A = ((racc[0] + racc[1]) + (racc[2] + racc[3]))
          + ((racc[4] + racc[5]) + (racc[6] + racc[7]));
    }

    // Pin x: opaque defs, not rematerializable, cannot be re-loaded.
    #pragma unroll
    for (int j = 0; j < 64; ++j) asm volatile("" : "+v"(x[j]));

    // Split-k base in an SGPR so the codebook address is provably wave-uniform.
    const int    kbase = __builtin_amdgcn_readfirstlane(half << 9);
    const float* cbp   = cb  + ((size_t)kbase << 6);
    const float* cs    = csq + kbase;

    float dmin = 3.402823466e38f;
    int   kmin = 0;

    #pragma unroll 1
    for (int kk = 0; kk < 512; kk += 4) {
        const float* e0 = cbp + (kk << 6);   // 4 contiguous entries = 1 KiB stream
        float m0 = 0.0f, m1 = 0.0f, m2 = 0.0f, m3 = 0.0f;
        #pragma unroll
        for (int j = 0; j < 64; ++j) {
            float xv = x[j];                 // one x access feeds 4 fmacs
            m0 = __builtin_fmaf(xv, e0[j      ], m0);
            m1 = __builtin_fmaf(xv, e0[j +  64], m1);
            m2 = __builtin_fmaf(xv, e0[j + 128], m2);
            m3 = __builtin_fmaf(xv, e0[j + 192], m3);
        }
        float d0, d1, d2, d3;
        {
            #pragma clang fp contract(off)
            d0 = (A - 2.0f * m0) + cs[kk    ];
            d1 = (A - 2.0f * m1) + cs[kk + 1];
            d2 = (A - 2.0f * m2) + cs[kk + 2];
            d3 = (A - 2.0f * m3) + cs[kk + 3];
        }
        // ascending k, strict < => first-index tie-break (numpy argmin)
        if (d0 < dmin) { dmin = d0; kmin = kk;     }
        if (d1 < dmin) { dmin = d1; kmin = kk + 1; }
        if (d2 < dmin) { dmin = d2; kmin = kk + 2; }
        if (d3 < dmin) { dmin = d3; kmin = kk + 3; }
    }

    __shared__ float ds[256];
    __shared__ int   ks[256];
    ds[tid] = dmin;
    ks[tid] = kmin;
    __syncthreads();

    float lsum = 0.0f;
    if (tid < 128) {
        float d0 = ds[tid], d1 = ds[tid + 128];
        int   k0 = ks[tid], k1 = ks[tid + 128] + 512;
        // full-scan equivalence: second half wins only on strict <
        int   code = (d1 < d0) ? k1 : k0;
        float db   = (d1 < d0) ? d1 : d0;
        codes_f[row] = (float)code;
        lsum = db;
    }
    __syncthreads();
    ds[tid] = lsum;                 // threads >=128 contribute 0
    __syncthreads();
    #pragma unroll
    for (int s = 128; s > 0; s >>= 1) {
        if (tid < s) ds[tid] += ds[tid + s];
        __syncthreads();
    }
    if (tid == 0) atomicAdd(loss_acc, ds[0]);
}

// Coalesced gather + straight-through write; lane 0 of the grid also
// finalizes the loss (argmin kernel has fully completed by stream order).
__global__ __launch_bounds__(256) void vq_quant(const float* __restrict__ in,
                                                const float* __restrict__ cb,
                                                const float* __restrict__ codes_f,
                                                float* __restrict__ out,
                                                const float* __restrict__ loss_acc,
                                                float* __restrict__ loss_out) {
    int t = blockIdx.x * 256 + threadIdx.x;   // one float4 per thread
    int row = t >> 4;                          // 16 threads per row
    int seg = t & 15;
    int code = (int)codes_f[row];
    const float4* q4 = (const float4*)(cb + ((size_t)code << 6));
    float4 xv = ((const float4*)in)[t];
    float4 qv = q4[seg];
    float4 st;
    {
        #pragma clang fp contract(off)
        st.x = xv.x + (qv.x - xv.x);
        st.y = xv.y + (qv.y - xv.y);
        st.z = xv.z + (qv.z - xv.z);
        st.w = xv.w + (qv.w - xv.w);
    }
    ((float4*)out)[t] = st;
    if (t == 0) {
        // loss = codebook_loss + BETA*commitment = 1.25 * mean((x-q)^2)
        loss_out[0] = 1.25f * loss_acc[0] / 8388608.0f;
    }
}

extern "C" void kernel_launch(void* const* d_in, const int* in_sizes, int n_in,
                              void* d_out, int out_size, void* d_ws, size_t ws_size,
                              hipStream_t stream) {
    const float* in = (const float*)d_in[0];   // (32,4096,64) fp32
    const float* cb = (const float*)d_in[1];   // (1024,64)    fp32
    float* out     = (float*)d_out;
    float* codes_f = out + 8388608;
    float* loss_p  = out + 8519680;
    float* ws      = (float*)d_ws;

    vq_prep  <<<4,    256, 0, stream>>>(cb, ws);
    vq_argmin<<<1024, 256, 0, stream>>>(in, cb, ws + 256, codes_f, ws);
    vq_quant <<<8192, 256, 0, stream>>>(in, cb, codes_f, out, ws, loss_p);
}

// Round 5
// 279.244 us; speedup vs baseline: 1.5337x; 1.5337x over previous
//
#include <hip/hip_runtime.h>

#define DIM   64
#define KCB   1024
#define RPB   256          // rows per block
#define SMEM_WORDS 18688   // 16384 x + 1024 dtab + 1024 ktab + 256 codes
#define SMEM_BYTES (SMEM_WORDS * 4)

// ws layout (floats): ws[0] = loss accumulator; ws[256..1279] = csq[k]

__global__ void vq_prep(const float* __restrict__ cb, float* __restrict__ ws) {
    int k = blockIdx.x * blockDim.x + threadIdx.x;
    if (k < KCB) {
        const float* e = cb + (k << 6);
        {
            #pragma clang fp contract(off)
            float racc[8];
            #pragma unroll
            for (int j = 0; j < 8; ++j) racc[j] = e[j] * e[j];
            #pragma unroll
            for (int t = 1; t < 8; ++t) {
                #pragma unroll
                for (int j = 0; j < 8; ++j) racc[j] += e[8 * t + j] * e[8 * t + j];
            }
            ws[256 + k] = ((racc[0] + racc[1]) + (racc[2] + racc[3]))
                        + ((racc[4] + racc[5]) + (racc[6] + racc[7]));
        }
    }
    if (k == 0) ws[0] = 0.0f;
}

// 2D register-tiled VQ kernel.
//  - 256 rows/block staged in LDS (XOR-swizzled: word = row*64 + ((cj^(row&15))*4)).
//  - wave w scans entry quarter [w*256, w*256+256); e addresses are uniform
//    (readfirstlane) -> scalar s_load_dwordx4 broadcast.
//  - each lane: 4 rows x 16 entries of accumulators; per 4-j step: 4 ds_read_b128
//    (a-frags) + 64 uniform e floats + 256 fmas -> per-e-element VALU overhead
//    amortized 4x over rows (R3/R4's per-entry ~64-107 slot overhead was the wall).
//  - per-dot j-chain strictly sequential (bit-identical to R1's passing kernel);
//    argmin = ascending strict-<, quarters lex-min combined ascending.
__global__ __launch_bounds__(256, 2) void vq_main(
        const float* __restrict__ in,
        const float* __restrict__ cb,
        const float* __restrict__ csq,      // = ws + 256
        float* __restrict__ codes_f,
        float* __restrict__ out,
        float* __restrict__ loss_acc)       // = ws + 0
{
    extern __shared__ float smem[];
    float* xs    = smem;                    // 16384 words, swizzled x
    float* dtab  = smem + 16384;            // 1024: per-row per-quarter best d
    int*   ktab  = (int*)(smem + 17408);    // 1024: per-row per-quarter best k
    int*   codes = (int*)(smem + 18432);    // 256

    const int tid  = threadIdx.x;
    const int lane = tid & 63;
    const int q    = __builtin_amdgcn_readfirstlane(tid >> 6);   // entry quarter
    const size_t rowBase = (size_t)blockIdx.x * RPB;

    // ---- stage x, swizzled ----
    {
        const float4* gx = (const float4*)(in + rowBase * DIM);
        #pragma unroll
        for (int i = 0; i < 16; ++i) {
            int idx = i * 256 + tid;
            int row = idx >> 4, cj = idx & 15;
            float4 v = gx[idx];
            *(float4*)(xs + row * 64 + ((cj ^ (row & 15)) << 2)) = v;
        }
    }
    __syncthreads();

    // ---- A = ||x||^2 for my 4 rows (exact numpy pairwise-8 order) ----
    float A[4];
    #pragma unroll
    for (int ri = 0; ri < 4; ++ri) {
        const int row = lane + (ri << 6);       // row&15 == lane&15
        float xv[64];
        #pragma unroll
        for (int cj = 0; cj < 16; ++cj) {
            float4 v = *(const float4*)(xs + row * 64 + ((cj ^ (lane & 15)) << 2));
            xv[cj*4+0]=v.x; xv[cj*4+1]=v.y; xv[cj*4+2]=v.z; xv[cj*4+3]=v.w;
        }
        {
            #pragma clang fp contract(off)
            float racc[8];
            #pragma unroll
            for (int j = 0; j < 8; ++j) racc[j] = xv[j] * xv[j];
            #pragma unroll
            for (int t = 1; t < 8; ++t) {
                #pragma unroll
                for (int j = 0; j < 8; ++j) racc[j] += xv[8*t+j] * xv[8*t+j];
            }
            A[ri] = ((racc[0] + racc[1]) + (racc[2] + racc[3]))
                  + ((racc[4] + racc[5]) + (racc[6] + racc[7]));
        }
    }

    // ---- main scan: my quarter's 256 entries, 16 at a time ----
    const float* cbq   = cb  + ((size_t)q << 14);   // q*256 entries * 64
    const float* csq_q = csq + (q << 8);
    float dmin[4] = {3.402823466e38f, 3.402823466e38f, 3.402823466e38f, 3.402823466e38f};
    int   kmin[4] = {0, 0, 0, 0};
    const int xb = lane * 64;

    #pragma unroll 1
    for (int ke = 0; ke < 256; ke += 16) {
        float m[4][16];
        #pragma unroll
        for (int ri = 0; ri < 4; ++ri)
            #pragma unroll
            for (int e = 0; e < 16; ++e) m[ri][e] = 0.0f;

        #pragma unroll 1
        for (int jb = 0; jb < 64; jb += 4) {
            const int slot4 = ((jb >> 2) ^ (lane & 15)) << 2;
            float4 a0 = *(const float4*)(xs + xb +         slot4);
            float4 a1 = *(const float4*)(xs + xb +  4096 + slot4);
            float4 a2 = *(const float4*)(xs + xb +  8192 + slot4);
            float4 a3 = *(const float4*)(xs + xb + 12288 + slot4);
            #pragma unroll
            for (int e = 0; e < 16; ++e) {
                float4 ev = *(const float4*)(cbq + ((ke + e) << 6) + jb); // uniform -> s_load
                m[0][e] = __builtin_fmaf(a0.x, ev.x, m[0][e]);
                m[0][e] = __builtin_fmaf(a0.y, ev.y, m[0][e]);
                m[0][e] = __builtin_fmaf(a0.z, ev.z, m[0][e]);
                m[0][e] = __builtin_fmaf(a0.w, ev.w, m[0][e]);
                m[1][e] = __builtin_fmaf(a1.x, ev.x, m[1][e]);
                m[1][e] = __builtin_fmaf(a1.y, ev.y, m[1][e]);
                m[1][e] = __builtin_fmaf(a1.z, ev.z, m[1][e]);
                m[1][e] = __builtin_fmaf(a1.w, ev.w, m[1][e]);
                m[2][e] = __builtin_fmaf(a2.x, ev.x, m[2][e]);
                m[2][e] = __builtin_fmaf(a2.y, ev.y, m[2][e]);
                m[2][e] = __builtin_fmaf(a2.z, ev.z, m[2][e]);
                m[2][e] = __builtin_fmaf(a2.w, ev.w, m[2][e]);
                m[3][e] = __builtin_fmaf(a3.x, ev.x, m[3][e]);
                m[3][e] = __builtin_fmaf(a3.y, ev.y, m[3][e]);
                m[3][e] = __builtin_fmaf(a3.z, ev.z, m[3][e]);
                m[3][e] = __builtin_fmaf(a3.w, ev.w, m[3][e]);
            }
        }

        #pragma unroll
        for (int e = 0; e < 16; ++e) {
            float cse = csq_q[ke + e];              // uniform
            int gk = (q << 8) + ke + e;
            #pragma unroll
            for (int ri = 0; ri < 4; ++ri) {
                float d;
                {
                    #pragma clang fp contract(off)
                    d = (A[ri] - 2.0f * m[ri][e]) + cse;
                }
                if (d < dmin[ri]) { dmin[ri] = d; kmin[ri] = gk; }  // ascending, strict <
            }
        }
    }

    // ---- cross-quarter lex-min combine ----
    #pragma unroll
    for (int ri = 0; ri < 4; ++ri) {
        int row = lane + (ri << 6);
        dtab[row * 4 + q] = dmin[ri];
        ktab[row * 4 + q] = kmin[ri];
    }
    __syncthreads();

    float db = dtab[tid * 4];
    int   kb = ktab[tid * 4];
    #pragma unroll
    for (int qq = 1; qq < 4; ++qq) {        // ascending quarters, strict <
        float dq = dtab[tid * 4 + qq];
        int   kq = ktab[tid * 4 + qq];
        if (dq < db) { db = dq; kb = kq; }
    }
    codes[tid] = kb;
    codes_f[rowBase + tid] = (float)kb;
    __syncthreads();

    // ---- fused straight-through write: st = x + (q - x) ----
    {
        float4* gout = (float4*)(out + rowBase * DIM);
        #pragma unroll
        for (int i = 0; i < 16; ++i) {
            int idx = i * 256 + tid;
            int row = idx >> 4, cj = idx & 15;
            int code = codes[row];
            float4 qv = *(const float4*)(cb + ((size_t)code << 6) + (cj << 2));
            float4 xv = *(const float4*)(xs + row * 64 + ((cj ^ (row & 15)) << 2));
            float4 st;
            {
                #pragma clang fp contract(off)
                st.x = xv.x + (qv.x - xv.x);
                st.y = xv.y + (qv.y - xv.y);
                st.z = xv.z + (qv.z - xv.z);
                st.w = xv.w + (qv.w - xv.w);
            }
            gout[idx] = st;
        }
    }

    // ---- loss partial (dtab reused as reduction tree) ----
    dtab[tid] = db;
    __syncthreads();
    #pragma unroll
    for (int s = 128; s > 0; s >>= 1) {
        if (tid < s) dtab[tid] += dtab[tid + s];
        __syncthreads();
    }
    if (tid == 0) atomicAdd(loss_acc, dtab[0]);
}

__global__ void vq_final(const float* __restrict__ ws, float* __restrict__ loss_out) {
    // loss = codebook_loss + BETA*commitment = 1.25 * mean((x-q)^2)
    loss_out[0] = 1.25f * ws[0] / 8388608.0f;
}

extern "C" void kernel_launch(void* const* d_in, const int* in_sizes, int n_in,
                              void* d_out, int out_size, void* d_ws, size_t ws_size,
                              hipStream_t stream) {
    const float* in = (const float*)d_in[0];   // (32,4096,64) fp32
    const float* cb = (const float*)d_in[1];   // (1024,64)    fp32
    float* out     = (float*)d_out;
    float* codes_f = out + 8388608;
    float* loss_p  = out + 8519680;
    float* ws      = (float*)d_ws;

    hipFuncSetAttribute((const void*)vq_main,
                        hipFuncAttributeMaxDynamicSharedMemorySize, SMEM_BYTES);

    vq_prep <<<4,   256, 0,          stream>>>(cb, ws);
    vq_main <<<512, 256, SMEM_BYTES, stream>>>(in, cb, ws + 256, codes_f, out, ws);
    vq_final<<<1,   1,   0,          stream>>>(ws, loss_p);
}